// Round 1
// baseline (132.258 us; speedup 1.0000x reference)
//
#include <hip/hip_runtime.h>

// Problem: B=8, Cin=64, H=W=128, Cout=64, K=9 taps at (i+0.4, j+0.4), i,j in 0..2.
// Reduces EXACTLY to a 4x4 conv with zero padding (clamp hits only zero rows/cols).
// Implicit GEMM: M = B*H*W = 131072, N = Cout = 64, K = Cin*16 = 1024, bf16 MFMA.

#define BATCH 8
#define CIN   64
#define COUT  64
#define HH    128
#define WW    128

typedef __attribute__((ext_vector_type(8))) short bf16x8;   // 8 bf16 = 4 VGPRs
typedef __attribute__((ext_vector_type(4))) float f32x4;

__device__ __forceinline__ unsigned short f2bf(float f) {
  unsigned int u = __float_as_uint(f);
  u = (u + 0x7fffu + ((u >> 16) & 1u)) >> 16;   // RNE
  return (unsigned short)u;
}

// ---------------------------------------------------------------------------
// Prep: W4[o][c][r][s] = sum_k w[o,c,k] * cy_k(r-iy_k) * cx_k(s-ix_k),
// stored as Wb[o][rs][c] bf16 (o*1024 + rs*64 + c) -- B-fragment friendly:
// lane reads 8 contiguous c at 16B-aligned addresses.
// ---------------------------------------------------------------------------
__global__ void make_wb(const float* __restrict__ wgt,
                        const float* __restrict__ off,
                        unsigned short* __restrict__ wb)
{
  int id = blockIdx.x * 256 + threadIdx.x;      // 4096 = 64*64
  int o = id >> 6, c = id & 63;
  float W16[16];
  #pragma unroll
  for (int i = 0; i < 16; ++i) W16[i] = 0.f;
  for (int k = 0; k < 9; ++k) {
    float dy = off[2*k], dx = off[2*k+1];
    float fyf = floorf(dy), fxf = floorf(dx);
    int   iy = (int)fyf,   ix = (int)fxf;       // in {0,1,2} for this problem
    float fy = dy - fyf,   fx = dx - fxf;
    float wk = wgt[(o*CIN + c)*9 + k];
    W16[(iy  )*4 + ix  ] += wk * (1.f-fy)*(1.f-fx);
    W16[(iy  )*4 + ix+1] += wk * (1.f-fy)*fx;
    W16[(iy+1)*4 + ix  ] += wk * fy*(1.f-fx);
    W16[(iy+1)*4 + ix+1] += wk * fy*fx;
  }
  for (int rs = 0; rs < 16; ++rs)
    wb[(o*16 + rs)*64 + c] = f2bf(W16[rs]);
}

// ---------------------------------------------------------------------------
// Main: per WG a 16x16 output tile (all 64 Cout). LDS holds the 19x19 halo'd
// input tile channel-last (stride 72 breaks bank conflicts). One staging
// barrier, then 32 barrier-free MFMA k-steps (rs=0..15 x c-half).
// ---------------------------------------------------------------------------
constexpr int CSTR = 72;                        // padded LDS channel stride

__global__ __launch_bounds__(256, 2)
void conv_mfma(const float* __restrict__ x,
               const unsigned short* __restrict__ wb,
               float* __restrict__ out)
{
  __shared__ unsigned short lt[19*19*CSTR];     // 51984 B

  const int wg = blockIdx.x;                    // 512 = 8 * 8 * 8
  const int b  = wg >> 6;
  const int y0 = ((wg >> 3) & 7) * 16;
  const int x0 = (wg & 7) * 16;
  const int t  = threadIdx.x;

  // ---- stage: lt[pos = row*19+col][c] = bf16(xpad[b, c, y0+row, x0+col]) ----
  // xpad row/col = x row/col + 1 (zero pad). pos-major across lanes => the
  // wave's simultaneous loads are consecutive columns (coalesced-ish).
  for (int rep = 0; rep < 2; ++rep) {
    int pos = t + rep*256;
    if (pos < 361) {
      int row = pos / 19;
      int col = pos - row*19;
      int gy = y0 + row - 1;                    // x-space row, [-1, 130]
      int gx = x0 + col - 1;
      bool ok = ((unsigned)gy < (unsigned)HH) && ((unsigned)gx < (unsigned)WW);
      int sgy = ok ? gy : 0;
      int sgx = ok ? gx : 0;
      float scale = ok ? 1.f : 0.f;
      const float* ps = x + ((size_t)(b*CIN)*HH + sgy)*WW + sgx;   // + c*HH*WW
      unsigned int* pd = (unsigned int*)&lt[pos*CSTR];
      #pragma unroll 8
      for (int c2 = 0; c2 < 32; ++c2) {
        float v0 = ps[(2*c2    )*HH*WW] * scale;
        float v1 = ps[(2*c2 + 1)*HH*WW] * scale;
        pd[c2] = (unsigned int)f2bf(v0) | ((unsigned int)f2bf(v1) << 16);
      }
    }
  }
  __syncthreads();

  // ---- compute ----
  const int lane = t & 63;
  const int wave = t >> 6;                      // wave handles rows yl = wave*4 + a
  const int m15  = lane & 15;                   // A: m (pixel col). B: n (o%16).
  const int q    = lane >> 4;                   // k-quad: c offset q*8

  f32x4 acc[4][4];
  #pragma unroll
  for (int a = 0; a < 4; ++a)
    #pragma unroll
    for (int n = 0; n < 4; ++n)
      acc[a][n] = (f32x4){0.f, 0.f, 0.f, 0.f};

  const unsigned short* wlane = wb + m15*1024 + q*8;  // + n*16*1024 + rs*64 + h*32

  #pragma unroll
  for (int h = 0; h < 2; ++h) {                 // c-half: c in [h*32, h*32+32)
    #pragma unroll
    for (int rs = 0; rs < 16; ++rs) {           // tap position r = rs>>2, s = rs&3
      const int r = rs >> 2, s = rs & 3;
      bf16x8 bfr[4], afr[4];
      #pragma unroll
      for (int n = 0; n < 4; ++n)
        bfr[n] = *(const bf16x8*)(wlane + n*16*1024 + rs*64 + h*32);
      #pragma unroll
      for (int a = 0; a < 4; ++a)
        afr[a] = *(const bf16x8*)(&lt[((wave*4 + a + r)*19 + (m15 + s))*CSTR + h*32 + q*8]);
      #pragma unroll
      for (int a = 0; a < 4; ++a)
        #pragma unroll
        for (int n = 0; n < 4; ++n)
          acc[a][n] = __builtin_amdgcn_mfma_f32_16x16x32_bf16(afr[a], bfr[n], acc[a][n], 0, 0, 0);
    }
  }

  // ---- epilogue: D layout col(lane&15)=o, row(q*4+reg)=pixel col ----
  #pragma unroll
  for (int a = 0; a < 4; ++a) {
    int yl = wave*4 + a;
    #pragma unroll
    for (int n = 0; n < 4; ++n) {
      int o = n*16 + m15;
      float* dst = out + (((size_t)(b*COUT + o))*HH + (y0 + yl))*WW + x0 + q*4;
      *(f32x4*)dst = acc[a][n];
    }
  }
}

// ---------------------------------------------------------------------------
extern "C" void kernel_launch(void* const* d_in, const int* in_sizes, int n_in,
                              void* d_out, int out_size, void* d_ws, size_t ws_size,
                              hipStream_t stream)
{
  const float* x   = (const float*)d_in[0];   // [8,64,128,128] fp32
  const float* wgt = (const float*)d_in[1];   // [64,64,9] fp32
  const float* off = (const float*)d_in[2];   // [9,2] fp32
  float* out = (float*)d_out;                 // [8,64,128,128] fp32
  unsigned short* wb = (unsigned short*)d_ws; // 64*1024 bf16 = 128 KB

  make_wb<<<16, 256, 0, stream>>>(wgt, off, wb);
  conv_mfma<<<512, 256, 0, stream>>>(x, wb, out);
}

// Round 2
// 125.521 us; speedup vs baseline: 1.0537x; 1.0537x over previous
//
#include <hip/hip_runtime.h>

// B=8, Cin=64, H=W=128, Cout=64, 9 bilinear taps at (i+0.4, j+0.4) == exact 4x4
// conv with zero pad. Implicit GEMM, bf16 MFMA 16x16x32.
//
// v2: full-width strip tiles. WG = (b, 2-row strip) x full W=128.
//   - staging reads whole 512B rows (lane-contiguous, all 256 threads active)
//   - channels in 2 passes of 32 (acc persists), LDS 5x132 cells of 40 shorts
//   - k-step = one tap (r,s), k = 32 channels; A-frag = one aligned ds_read_b128

#define CIN   64
#define COUT  64
#define HH    128
#define WW    128

typedef __attribute__((ext_vector_type(8))) short bf16x8;   // 8 bf16 = 4 VGPRs
typedef __attribute__((ext_vector_type(4))) float f32x4;
typedef __attribute__((ext_vector_type(4))) unsigned int u32x4;

__device__ __forceinline__ unsigned short f2bf(float f) {
  unsigned int u = __float_as_uint(f);
  u = (u + 0x7fffu + ((u >> 16) & 1u)) >> 16;   // RNE
  return (unsigned short)u;
}

// ---------------------------------------------------------------------------
// W4[o][c][r][s] = sum_k w[o,c,k] * cy_k(r-iy_k) * cx_k(s-ix_k), stored as
// wb[o][rs][c] bf16 -- B-fragment reads 8 contiguous c, 16B aligned.
// ---------------------------------------------------------------------------
__global__ void make_wb(const float* __restrict__ wgt,
                        const float* __restrict__ off,
                        unsigned short* __restrict__ wb)
{
  int id = blockIdx.x * 64 + threadIdx.x;       // 4096 = 64*64
  int o = id >> 6, c = id & 63;
  float W16[16];
  #pragma unroll
  for (int i = 0; i < 16; ++i) W16[i] = 0.f;
  for (int k = 0; k < 9; ++k) {
    float dy = off[2*k], dx = off[2*k+1];
    float fyf = floorf(dy), fxf = floorf(dx);
    int   iy = (int)fyf,   ix = (int)fxf;       // in {0,1,2}
    float fy = dy - fyf,   fx = dx - fxf;
    float wk = wgt[(o*CIN + c)*9 + k];
    W16[(iy  )*4 + ix  ] += wk * (1.f-fy)*(1.f-fx);
    W16[(iy  )*4 + ix+1] += wk * (1.f-fy)*fx;
    W16[(iy+1)*4 + ix  ] += wk * fy*(1.f-fx);
    W16[(iy+1)*4 + ix+1] += wk * fy*fx;
  }
  for (int rs = 0; rs < 16; ++rs)
    wb[(o*16 + rs)*64 + c] = f2bf(W16[rs]);
}

// ---------------------------------------------------------------------------
constexpr int CS    = 40;                       // shorts per (row,col) cell (80 B)
constexpr int LCOLS = 132;                      // lcol = gx+1, gx in -1..130

__global__ __launch_bounds__(256, 2)
void conv_mfma(const float* __restrict__ x,
               const unsigned short* __restrict__ wb,
               float* __restrict__ out)
{
  __shared__ unsigned short lt[5 * LCOLS * CS]; // 52800 B

  const int wg = blockIdx.x;                    // 512 = 8 b * 64 strips
  const int b  = wg >> 6;
  const int y0 = (wg & 63) * 2;
  const int t  = threadIdx.x;
  const int lane = t & 63;
  const int wave = t >> 6;                      // wave = x-tile index 0..7? no: 4 waves
  const int m15  = lane & 15;
  const int q    = lane >> 4;

  // 4 waves; each wave owns TWO x-tiles (xt = wave*2 + xi), 2 y-rows, 4 n-tiles
  f32x4 acc[2][2][4];
  #pragma unroll
  for (int xi = 0; xi < 2; ++xi)
    #pragma unroll
    for (int yl = 0; yl < 2; ++yl)
      #pragma unroll
      for (int n = 0; n < 4; ++n)
        acc[xi][yl][n] = (f32x4){0.f, 0.f, 0.f, 0.f};

  #pragma unroll
  for (int p = 0; p < 2; ++p) {                 // channel pass: c in [32p, 32p+32)
    if (p) __syncthreads();                     // all reads of pass 0 done

    // ---- zero-fill edge columns (lcol 0, 129, 130, 131) for this pass ----
    if (t < 80) {
      int row  = t >> 4;
      int rem  = t & 15;
      int csel = rem >> 2;
      int col  = (csel == 0) ? 0 : (128 + csel);
      int chnk = rem & 3;
      *(u32x4*)&lt[(row*LCOLS + col)*CS + chnk*8] = (u32x4){0u,0u,0u,0u};
    }

    // ---- stage: 40 wave-items = 5 rows x 4 chunks(8ch) x 2 x-halves ----
    for (int it = wave; it < 40; it += 4) {
      int row  = it >> 3;                       // 0..4
      int rem  = it & 7;
      int chnk = rem >> 1;                      // 8-channel chunk
      int xh   = rem & 1;
      int xcol = xh*64 + lane;                  // gx = xcol, 0..127
      int gy   = y0 + row - 1;                  // -1..129
      unsigned int pk[4];
      if ((unsigned)gy < (unsigned)HH) {
        const float* ps = x + ((size_t)((b*CIN + p*32 + chnk*8)*HH + gy))*WW + xcol;
        float v[8];
        #pragma unroll
        for (int cc = 0; cc < 8; ++cc) v[cc] = ps[cc*HH*WW];
        #pragma unroll
        for (int i = 0; i < 4; ++i)
          pk[i] = (unsigned int)f2bf(v[2*i]) | ((unsigned int)f2bf(v[2*i+1]) << 16);
      } else {
        pk[0] = pk[1] = pk[2] = pk[3] = 0u;
      }
      *(u32x4*)&lt[(row*LCOLS + xcol + 1)*CS + chnk*8] = *(u32x4*)pk;
    }
    __syncthreads();

    // ---- compute: 16 k-steps, one tap (r,s) each, k = 32 channels ----
    #pragma unroll
    for (int rs = 0; rs < 16; ++rs) {
      const int r = rs >> 2, s = rs & 3;
      bf16x8 bfr[4];
      #pragma unroll
      for (int n = 0; n < 4; ++n)
        bfr[n] = *(const bf16x8*)(wb + ((n*16 + m15)*16 + rs)*64 + p*32 + q*8);
      #pragma unroll
      for (int xi = 0; xi < 2; ++xi) {
        const int xt = wave*2 + xi;
        #pragma unroll
        for (int yl = 0; yl < 2; ++yl) {
          bf16x8 afr = *(const bf16x8*)(&lt[((yl + r)*LCOLS + (xt*16 + m15 + s))*CS + q*8]);
          #pragma unroll
          for (int n = 0; n < 4; ++n)
            acc[xi][yl][n] = __builtin_amdgcn_mfma_f32_16x16x32_bf16(afr, bfr[n], acc[xi][yl][n], 0, 0, 0);
        }
      }
    }
  }

  // ---- epilogue: D layout col(lane&15)=o, row(q*4+reg)=pixel x ----
  #pragma unroll
  for (int xi = 0; xi < 2; ++xi) {
    const int xt = wave*2 + xi;
    #pragma unroll
    for (int yl = 0; yl < 2; ++yl) {
      #pragma unroll
      for (int n = 0; n < 4; ++n) {
        int o = n*16 + m15;
        float* dst = out + (((size_t)(b*COUT + o))*HH + (y0 + yl))*WW + xt*16 + q*4;
        *(f32x4*)dst = acc[xi][yl][n];
      }
    }
  }
}

// ---------------------------------------------------------------------------
extern "C" void kernel_launch(void* const* d_in, const int* in_sizes, int n_in,
                              void* d_out, int out_size, void* d_ws, size_t ws_size,
                              hipStream_t stream)
{
  const float* x   = (const float*)d_in[0];   // [8,64,128,128] fp32
  const float* wgt = (const float*)d_in[1];   // [64,64,9] fp32
  const float* off = (const float*)d_in[2];   // [9,2] fp32
  float* out = (float*)d_out;                 // [8,64,128,128] fp32
  unsigned short* wb = (unsigned short*)d_ws; // 64*16*64 bf16 = 128 KB

  make_wb<<<64, 64, 0, stream>>>(wgt, off, wb);
  conv_mfma<<<512, 256, 0, stream>>>(x, wb, out);
}

// Round 3
// 108.358 us; speedup vs baseline: 1.2206x; 1.1584x over previous
//
#include <hip/hip_runtime.h>

// B=8, Cin=64, H=W=128, Cout=64, 9 bilinear taps at (i+0.4, j+0.4) == exact 4x4
// conv with zero pad. Implicit GEMM, bf16 MFMA 16x16x32.
//
// v3: latency-oriented restructure.
//   - wb2 = B-fragment STREAM layout: each (p,rs,n) slice is 1 KB contiguous,
//     lane reads base + lane*16B (one coalesced dwordx4 per fragment).
//   - 1-row strips, WG=128 threads (2 waves), grid 1024 -> 4 blocks/CU.
//   - wave computes 64 px x 64 Cout: acc[4][4] f32x4 (64 VGPRs), at 2 waves/SIMD
//     VGPR budget 256 -> deep compiler pipelining.
//   - LDS cell = 32 ch (64 B), XOR slot swizzle (chunk+(pos>>2))&3: conflict-free
//     b128 writes AND reads; 33792 B/block -> 4 blocks/CU.
//   - XCD y-band swizzle for halo L2 reuse; coalesced epilogue via LDS transpose.

#define CIN   64
#define COUT  64
#define HH    128
#define WW    128

typedef __attribute__((ext_vector_type(8))) short bf16x8;   // 8 bf16 = 4 VGPRs
typedef __attribute__((ext_vector_type(4))) float f32x4;
typedef __attribute__((ext_vector_type(4))) unsigned int u32x4;

__device__ __forceinline__ unsigned short f2bf(float f) {
  unsigned int u = __float_as_uint(f);
  u = (u + 0x7fffu + ((u >> 16) & 1u)) >> 16;   // RNE
  return (unsigned short)u;
}

// ---------------------------------------------------------------------------
// W4[o][c][r][s] = sum_k w[o,c,k] * cy_k(r-iy_k) * cx_k(s-ix_k).
// Stream layout: wb2[(((p*16+rs)*4 + n)*64 + lane)*8 + j] where consuming lane
// l holds o = n*16 + (l&15), ch = p*32 + (l>>4)*8 + j, for tap rs.
// ---------------------------------------------------------------------------
__global__ void make_wb(const float* __restrict__ wgt,
                        const float* __restrict__ off,
                        unsigned short* __restrict__ wb2)
{
  int id = blockIdx.x * 64 + threadIdx.x;       // 4096 = 64*64
  int o = id >> 6, c = id & 63;
  float W16[16];
  #pragma unroll
  for (int i = 0; i < 16; ++i) W16[i] = 0.f;
  for (int k = 0; k < 9; ++k) {
    float dy = off[2*k], dx = off[2*k+1];
    float fyf = floorf(dy), fxf = floorf(dx);
    int   iy = (int)fyf,   ix = (int)fxf;       // in {0,1,2}
    float fy = dy - fyf,   fx = dx - fxf;
    float wk = wgt[(o*CIN + c)*9 + k];
    W16[(iy  )*4 + ix  ] += wk * (1.f-fy)*(1.f-fx);
    W16[(iy  )*4 + ix+1] += wk * (1.f-fy)*fx;
    W16[(iy+1)*4 + ix  ] += wk * fy*(1.f-fx);
    W16[(iy+1)*4 + ix+1] += wk * fy*fx;
  }
  int p = c >> 5, q = (c >> 3) & 3, j = c & 7;
  int n = o >> 4, m15 = o & 15;
  int lanei = q*16 + m15;
  for (int rs = 0; rs < 16; ++rs)
    wb2[(size_t)(((p*16 + rs)*4 + n)*64 + lanei)*8 + j] = f2bf(W16[rs]);
}

// ---------------------------------------------------------------------------
// conv: WG = 128 threads (2 waves), tile = 1 output row x 128 px x 64 Cout.
// LDS tile: 4 rows x 132 cols x 32 ch(bf16) with XOR slot swizzle. 33792 B.
// ---------------------------------------------------------------------------
__global__ __launch_bounds__(128, 2)   // 2 waves/EU -> 4 blocks/CU
void conv_mfma(const float* __restrict__ x,
               const unsigned short* __restrict__ wb2,
               float* __restrict__ out)
{
  __shared__ unsigned short tile[4 * 132 * 32]; // 33792 B (also epilogue f32 buf)

  const int wg  = blockIdx.x;                   // 1024
  const int xcd = wg & 7;
  const int i8  = wg >> 3;                      // 0..127
  const int b   = i8 >> 4;
  const int y0  = xcd * 16 + (i8 & 15);         // XCD-local 16-row band
  const int t    = threadIdx.x;
  const int wave = t >> 6;                      // 0..1
  const int lane = t & 63;
  const int m15  = lane & 15;
  const int q    = lane >> 4;

  f32x4 acc[4][4];
  #pragma unroll
  for (int mi = 0; mi < 4; ++mi)
    #pragma unroll
    for (int n = 0; n < 4; ++n)
      acc[mi][n] = (f32x4){0.f, 0.f, 0.f, 0.f};

  #pragma unroll
  for (int p = 0; p < 2; ++p) {                 // channel pass: c in [32p, 32p+32)
    if (p) __syncthreads();                     // pass-0 tile reads complete

    if (p == 0) {                               // zero edge cells (cols 0,129,130,131)
      int row = t >> 5, rem = t & 31;
      int csel = rem >> 3;
      int col  = (csel == 0) ? 0 : (128 + csel);
      int w8   = rem & 7;
      *(unsigned long long*)&tile[(row*132 + col)*32 + w8*4] = 0ull;
    }

    // ---- stage: 32 items = 4 rows x 4 chunks(8ch) x 2 x-halves ----
    #pragma unroll 4
    for (int it = 0; it < 16; ++it) {
      int g     = it*2 + wave;                  // 0..31
      int row   = g >> 3;                       // 0..3
      int rem   = g & 7;
      int chunk = rem >> 1;                     // 8-ch chunk within pass
      int xh    = rem & 1;
      int px    = xh*64 + lane;                 // 0..127
      int gy    = y0 + row - 1;                 // -1..129
      unsigned int pk[4];
      if ((unsigned)gy < (unsigned)HH) {
        const float* ps = x + ((size_t)((b*CIN + p*32 + chunk*8)*HH + gy))*WW + px;
        float v[8];
        #pragma unroll
        for (int cc = 0; cc < 8; ++cc) v[cc] = ps[(size_t)cc*HH*WW];
        #pragma unroll
        for (int i = 0; i < 4; ++i)
          pk[i] = (unsigned int)f2bf(v[2*i]) | ((unsigned int)f2bf(v[2*i+1]) << 16);
      } else {
        pk[0] = pk[1] = pk[2] = pk[3] = 0u;
      }
      int pos  = px + 1;
      int slot = (chunk + (pos >> 2)) & 3;      // XOR bank swizzle
      *(u32x4*)&tile[((row*132 + pos)*4 + slot)*8] = *(u32x4*)pk;
    }
    __syncthreads();

    // ---- compute: 16 rs steps; B = contiguous stream loads, A = swizzled LDS ----
    const unsigned short* wstream = wb2 + (size_t)p*16*4*512 + lane*8;
    #pragma unroll
    for (int rs = 0; rs < 16; ++rs) {
      const int r = rs >> 2, s = rs & 3;
      bf16x8 bfr[4];
      #pragma unroll
      for (int n = 0; n < 4; ++n)
        bfr[n] = *(const bf16x8*)(wstream + (rs*4 + n)*512);
      bf16x8 afr[4];
      #pragma unroll
      for (int mi = 0; mi < 4; ++mi) {
        int pos  = wave*64 + mi*16 + m15 + s;
        int slot = (q + (pos >> 2)) & 3;
        afr[mi] = *(const bf16x8*)(&tile[((r*132 + pos)*4 + slot)*8]);
      }
      #pragma unroll
      for (int mi = 0; mi < 4; ++mi)
        #pragma unroll
        for (int n = 0; n < 4; ++n)
          acc[mi][n] = __builtin_amdgcn_mfma_f32_16x16x32_bf16(afr[mi], bfr[n], acc[mi][n], 0, 0, 0);
    }
  }

  // ---- epilogue: transpose through LDS for coalesced stores ----
  __syncthreads();                              // all tile reads done
  float* epi = (float*)tile;                    // [64 o][132 px] = 33792 B
  #pragma unroll
  for (int mi = 0; mi < 4; ++mi)
    #pragma unroll
    for (int n = 0; n < 4; ++n) {
      int o  = n*16 + m15;
      int px = wave*64 + mi*16 + q*4;           // D row = q*4 + reg
      *(f32x4*)&epi[o*132 + px] = acc[mi][n];
    }
  __syncthreads();
  #pragma unroll
  for (int i = 0; i < 16; ++i) {
    int o  = i*4 + (t >> 5);
    int px = (t & 31) * 4;
    f32x4 v = *(const f32x4*)&epi[o*132 + px];
    *(f32x4*)&out[(((size_t)(b*COUT + o))*HH + y0)*WW + px] = v;
  }
}

// ---------------------------------------------------------------------------
extern "C" void kernel_launch(void* const* d_in, const int* in_sizes, int n_in,
                              void* d_out, int out_size, void* d_ws, size_t ws_size,
                              hipStream_t stream)
{
  const float* x   = (const float*)d_in[0];   // [8,64,128,128] fp32
  const float* wgt = (const float*)d_in[1];   // [64,64,9] fp32
  const float* off = (const float*)d_in[2];   // [9,2] fp32
  float* out = (float*)d_out;                 // [8,64,128,128] fp32
  unsigned short* wb2 = (unsigned short*)d_ws;// 128 KB stream-layout weights

  make_wb<<<64, 64, 0, stream>>>(wgt, off, wb2);
  conv_mfma<<<1024, 128, 0, stream>>>(x, wb2, out);
}